// Round 10
// baseline (106.534 us; speedup 1.0000x reference)
//
#include <hip/hip_runtime.h>

// B=256, F=32, N=16, D=512
//   sims[b,f,c,n] = relu(face[b,f]·ner[c,n])      (8192 x 4096 NT GEMM, K=512)
//   S_all[b,f]    = sum_{c,n} masked(sims)        (masked: ==1.0 -> 0)
//   pos[b,f]      = sum_n sims[b,f,b,n]           (unmasked diagonal)
//   diag_m[b,f]   = sum_n masked(sims[b,f,b,n])
//   loss = sum(relu((S_all-diag_m)/255 - pos + 0.2) * face_mask) / 256
//
// Round 10: barrier-free flat GEMM (r5 idea, VGPR-cap bug fixed).
// Block = 256 thr (4 waves), output 256 rows x 64 cols; wave-tile 64x64.
// B panel (64 cols x 512 K, 64 KB static LDS) staged once via global_load_lds
// with XOR k-slot swizzle; A streams global->VGPR with 3-deep rotating
// prefetch; B-frags double-buffered. NO barriers in K-loop -- compiler
// emits counted vmcnt/lgkmcnt; waves pipeline independently; 2 blocks/CU.
// LDS traffic halved vs r2 (A never touches LDS). Diag fused; merged cvt.

#define DIM_D 512
#define M_TOT 8192
#define N_TOT 4096

typedef __attribute__((ext_vector_type(8))) short short8v;
typedef __attribute__((ext_vector_type(4))) float f32x4;

__device__ __forceinline__ unsigned short f2bf(float f) {
  unsigned int u = __builtin_bit_cast(unsigned int, f);
  u += 0x7fffu + ((u >> 16) & 1u);
  return (unsigned short)(u >> 16);
}

// ---------------------------------------------------------------------------
// Merged cvt: face+ner fp32 -> bf16, plus face_mask (fp32 row-sum != 0).
// ---------------------------------------------------------------------------
__global__ __launch_bounds__(256) void cvt_all(
    const float* __restrict__ face, const float* __restrict__ ner,
    unsigned short* __restrict__ face_bf, unsigned short* __restrict__ ner_bf,
    float* __restrict__ mask) {
  const int gw = blockIdx.x * 4 + (threadIdx.x >> 6);
  const int lane = threadIdx.x & 63;
  const bool isFace = gw < M_TOT;
  const int row = isFace ? gw : gw - M_TOT;
  const float* src = (isFace ? face : ner) + (size_t)row * DIM_D;
  unsigned short* dst = (isFace ? face_bf : ner_bf) + (size_t)row * DIM_D;

  const float4 f0 = ((const float4*)src)[lane * 2];
  const float4 f1 = ((const float4*)src)[lane * 2 + 1];
  short8v o;
  o[0] = (short)f2bf(f0.x); o[1] = (short)f2bf(f0.y);
  o[2] = (short)f2bf(f0.z); o[3] = (short)f2bf(f0.w);
  o[4] = (short)f2bf(f1.x); o[5] = (short)f2bf(f1.y);
  o[6] = (short)f2bf(f1.z); o[7] = (short)f2bf(f1.w);
  *(short8v*)(dst + lane * 8) = o;

  if (isFace) {
    float fs = f0.x + f0.y + f0.z + f0.w + f1.x + f1.y + f1.z + f1.w;
#pragma unroll
    for (int off = 1; off < 64; off <<= 1) fs += __shfl_xor(fs, off);
    if (lane == 0) mask[row] = (fs != 0.0f) ? 1.0f : 0.0f;
  }
}

// ---------------------------------------------------------------------------
// Flat GEMM.
// LDS: B panel, col c at [c*512, (c+1)*512) shorts. Content k-slot s (16B,
// s in [0,64)) of col c stored at position s ^ (c&7)  -> ds_read_b128 spreads
// 16 col-lanes over 8 bank-quads (2-way alias = free, m136).
// Staged: lane l of col-c instr writes pos l, so source k-slot = l ^ (c&7)
// (pre-swizzled global source, linear LDS dst -- rule #21).
// A fragment (wave row-block 64): row = m0 + wid*64 + mi*16 + (lane&15),
// k-bytes t*64 + (lane>>4)*16 -> global_load_dwordx4, 64B/row granule.
// ---------------------------------------------------------------------------
#define MFMA(A_, B_, C_) __builtin_amdgcn_mfma_f32_16x16x32_bf16(A_, B_, C_, 0, 0, 0)

__global__ __launch_bounds__(256, 2) void grl_flat(
    const unsigned short* __restrict__ A, const unsigned short* __restrict__ Bn,
    float* __restrict__ S_all, float* __restrict__ pos,
    float* __restrict__ diagm) {
  __shared__ __align__(16) unsigned short Blds[64 * 512];  // 64 KB

  const int tid = threadIdx.x;
  const int lane = tid & 63;
  const int wid = tid >> 6;
  const int n0 = blockIdx.x * 64;   // 0..4032
  const int m0 = blockIdx.y * 256;  // 0..7936

  // ---- stage B panel once: 16 global_load_lds per wave ------------------
#pragma unroll
  for (int i = 0; i < 16; ++i) {
    const int c = wid * 16 + i;     // c&7 == i&7
    const unsigned short* src = Bn + (size_t)(n0 + c) * DIM_D + (lane ^ (i & 7)) * 8;
    __builtin_amdgcn_global_load_lds(
        (const __attribute__((address_space(1))) void*)src,
        (__attribute__((address_space(3))) void*)(Blds + c * 512), 16, 0, 0);
  }
  __syncthreads();  // drains vmcnt(0); the ONLY barrier in this kernel

  // ---- per-lane bases ---------------------------------------------------
  const unsigned short* pA =
      A + (size_t)(m0 + wid * 64 + (lane & 15)) * DIM_D + (lane >> 4) * 8;
  const unsigned short* pB = Blds + (lane & 15) * 512;
  const int khl = lane >> 4;  // k quad
  const int klo = lane & 7;   // swizzle key

#define LOADA(SET, T)                                                   \
  _Pragma("unroll") for (int mi_ = 0; mi_ < 4; ++mi_)                   \
      SET[mi_] = *(const short8v*)(pA + mi_ * (16 * DIM_D) + (T) * 32);

#define LOADB(SET, T)                                                   \
  _Pragma("unroll") for (int ni_ = 0; ni_ < 4; ++ni_)                   \
      SET[ni_] = *(const short8v*)(pB + ni_ * (16 * 512) +              \
                                   (((T) * 4 + khl) ^ klo) * 8);

#define MFMA16(AS, BS)                                                  \
  _Pragma("unroll") for (int ni_ = 0; ni_ < 4; ++ni_)                   \
      _Pragma("unroll") for (int mi_ = 0; mi_ < 4; ++mi_)               \
          acc[mi_][ni_] = MFMA(AS[mi_], BS[ni_], acc[mi_][ni_]);

  f32x4 acc[4][4];
#pragma unroll
  for (int i = 0; i < 4; ++i)
#pragma unroll
    for (int j = 0; j < 4; ++j) acc[i][j] = (f32x4){0.f, 0.f, 0.f, 0.f};

  short8v aP[4], aQ[4], aR[4], bP[4], bQ[4];

  // ---- prologue: A(0),A(1) in flight; B(0) read -------------------------
  LOADA(aP, 0);
  LOADA(aQ, 1);
  LOADB(bP, 0);

  // ---- 16 K-steps, zero barriers; A rotates P,Q,R; B ping-pongs ---------
  LOADA(aR, 2);  LOADB(bQ, 1);  MFMA16(aP, bP);   // t=0
  LOADA(aP, 3);  LOADB(bP, 2);  MFMA16(aQ, bQ);   // t=1
  LOADA(aQ, 4);  LOADB(bQ, 3);  MFMA16(aR, bP);   // t=2
  LOADA(aR, 5);  LOADB(bP, 4);  MFMA16(aP, bQ);   // t=3
  LOADA(aP, 6);  LOADB(bQ, 5);  MFMA16(aQ, bP);   // t=4
  LOADA(aQ, 7);  LOADB(bP, 6);  MFMA16(aR, bQ);   // t=5
  LOADA(aR, 8);  LOADB(bQ, 7);  MFMA16(aP, bP);   // t=6
  LOADA(aP, 9);  LOADB(bP, 8);  MFMA16(aQ, bQ);   // t=7
  LOADA(aQ, 10); LOADB(bQ, 9);  MFMA16(aR, bP);   // t=8
  LOADA(aR, 11); LOADB(bP, 10); MFMA16(aP, bQ);   // t=9
  LOADA(aP, 12); LOADB(bQ, 11); MFMA16(aQ, bP);   // t=10
  LOADA(aQ, 13); LOADB(bP, 12); MFMA16(aR, bQ);   // t=11
  LOADA(aR, 14); LOADB(bQ, 13); MFMA16(aP, bP);   // t=12
  LOADA(aP, 15); LOADB(bP, 14); MFMA16(aQ, bQ);   // t=13
                 LOADB(bQ, 15); MFMA16(aR, bP);   // t=14
                                MFMA16(aP, bQ);   // t=15

  // ---- fused relu + (==1 -> 0) + per-thread row sums --------------------
  // C/D layout: col = lane&15 (n), row(frag) = (lane>>4)*4 + reg
  float rs[4][4];
#pragma unroll
  for (int mi = 0; mi < 4; ++mi)
#pragma unroll
    for (int r = 0; r < 4; ++r) rs[mi][r] = 0.0f;
#pragma unroll
  for (int mi = 0; mi < 4; ++mi)
#pragma unroll
    for (int ni = 0; ni < 4; ++ni)
#pragma unroll
      for (int r = 0; r < 4; ++r) {
        float v = acc[mi][ni][r];
        v = v > 0.0f ? v : 0.0f;
        v = (v == 1.0f) ? 0.0f : v;
        rs[mi][r] += v;
      }
#pragma unroll
  for (int mi = 0; mi < 4; ++mi)
#pragma unroll
    for (int r = 0; r < 4; ++r) {
      float s = rs[mi][r];
      s += __shfl_xor(s, 1);
      s += __shfl_xor(s, 2);
      s += __shfl_xor(s, 4);
      s += __shfl_xor(s, 8);
      if ((lane & 15) == 0)
        atomicAdd(&S_all[m0 + wid * 64 + mi * 16 + (lane >> 4) * 4 + r], s);
    }

  // ---- fused diagonal: rows R0..R0+15 share b_ = R0>>5; its 16 diag cols
  // [16*b_, +16) fall in this block's panel iff 0 <= tc < 64 ----------------
#pragma unroll
  for (int mi = 0; mi < 4; ++mi) {
    const int R0 = m0 + wid * 64 + mi * 16;
    const int tc = ((R0 >> 5) << 4) - n0;
    if (tc >= 0 && tc < 64) {
      const int dn = tc >> 4;
#pragma unroll
      for (int ni = 0; ni < 4; ++ni)
        if (ni == dn) {
#pragma unroll
          for (int r = 0; r < 4; ++r) {
            float v = acc[mi][ni][r];
            v = v > 0.0f ? v : 0.0f;
            float vm = (v == 1.0f) ? 0.0f : v;
            float ps = v, ds = vm;
            ps += __shfl_xor(ps, 1); ds += __shfl_xor(ds, 1);
            ps += __shfl_xor(ps, 2); ds += __shfl_xor(ds, 2);
            ps += __shfl_xor(ps, 4); ds += __shfl_xor(ds, 4);
            ps += __shfl_xor(ps, 8); ds += __shfl_xor(ds, 8);
            if ((lane & 15) == 0) {
              const int R = R0 + (lane >> 4) * 4 + r;
              pos[R] = ps;
              diagm[R] = ds;
            }
          }
        }
    }
  }
}

// ---------------------------------------------------------------------------
// Finalize: rank + global sum. Single block, 1024 threads.
// ---------------------------------------------------------------------------
__global__ __launch_bounds__(1024) void grl_final(
    const float* __restrict__ S_all, const float* __restrict__ diagm,
    const float* __restrict__ pos, const float* __restrict__ mask,
    float* __restrict__ out) {
  __shared__ float red[16];
  const int lane = threadIdx.x & 63;
  const int wv = threadIdx.x >> 6;
  float s = 0.0f;
  for (int r = threadIdx.x; r < M_TOT; r += 1024) {
    const float neg = (S_all[r] - diagm[r]) / 255.0f;  // 255 + 1e-8 == 255.0f
    float rank = neg - pos[r] + 0.2f;
    rank = rank > 0.0f ? rank : 0.0f;
    s += rank * mask[r];
  }
#pragma unroll
  for (int off = 1; off < 64; off <<= 1) s += __shfl_xor(s, off);
  if (lane == 0) red[wv] = s;
  __syncthreads();
  if (threadIdx.x == 0) {
    float t = 0.0f;
#pragma unroll
    for (int i = 0; i < 16; ++i) t += red[i];
    out[0] = t / 256.0f;  // BETA * sum / B
  }
}

// ---------------------------------------------------------------------------
extern "C" void kernel_launch(void* const* d_in, const int* in_sizes, int n_in,
                              void* d_out, int out_size, void* d_ws, size_t ws_size,
                              hipStream_t stream) {
  const float* face = (const float*)d_in[0];
  const float* ner = (const float*)d_in[1];

  unsigned short* face_bf = (unsigned short*)d_ws;
  unsigned short* ner_bf = face_bf + (size_t)M_TOT * DIM_D;
  float* S_all = (float*)(ner_bf + (size_t)N_TOT * DIM_D);
  float* diagm = S_all + M_TOT;
  float* pos = diagm + M_TOT;
  float* mask = pos + M_TOT;

  hipMemsetAsync(S_all, 0, M_TOT * sizeof(float), stream);
  cvt_all<<<(M_TOT + N_TOT) / 4, 256, 0, stream>>>(face, ner, face_bf, ner_bf,
                                                   mask);
  grl_flat<<<dim3(N_TOT / 64, M_TOT / 256), 256, 0, stream>>>(
      face_bf, ner_bf, S_all, pos, diagm);
  grl_final<<<1, 1024, 0, stream>>>(S_all, diagm, pos, mask, (float*)d_out);
}